// Round 6
// baseline (961.732 us; speedup 1.0000x reference)
//
#include <hip/hip_runtime.h>

#define NV   50000
#define FD   128
#define NE   800000
#define NOUT 64
#define NBIN 196          // ceil(NV/256) coarse buckets of 256 nodes
#define CH   2048         // edges per block in P0/P1
#define NBLK 391          // ceil(NE/CH)
#define SCAN_L (NBIN * NBLK)
#define SCHUNK 2048       // elements per block in hierarchical scan
#define NSCH ((SCAN_L + SCHUNK - 1) / SCHUNK)   // 38
#define CAP2 12288        // LDS staging cap in P2 (avg span ~4083)
#define NSLICE 8          // feature slices (one per XCD), 16 dims each
#define SDIM 16

typedef unsigned short bf16_t;
typedef unsigned short u16;
typedef unsigned char  u8;
typedef __attribute__((ext_vector_type(8))) short bf16x8;
typedef __attribute__((ext_vector_type(4))) float f32x4;

__device__ __forceinline__ bf16_t f2bf(float f) {
  unsigned u = __builtin_bit_cast(unsigned, f);
  return (bf16_t)((u + 0x7fffu + ((u >> 16) & 1u)) >> 16);
}
__device__ __forceinline__ float bflo(unsigned v) { return __builtin_bit_cast(float, v << 16); }
__device__ __forceinline__ float bfhi(unsigned v) { return __builtin_bit_cast(float, v & 0xffff0000u); }

struct Ptr4 { const int* p[4]; };

// ================= bucket-sort based CSR build (no global atomics) =================

__global__ __launch_bounds__(256) void p0_hist(Ptr4 rows, Ptr4 cols,
                                               int* __restrict__ blockCnt) {
  const int r = blockIdx.y, blk = blockIdx.x, t = threadIdx.x;
  __shared__ int cd[NBIN], cs[NBIN];
  for (int i = t; i < NBIN; i += 256) { cd[i] = 0; cs[i] = 0; }
  __syncthreads();
  const int e0 = blk * CH;
  const int n = min(CH, NE - e0);
  const int* rw = rows.p[r] + e0;
  const int* cl = cols.p[r] + e0;
  for (int i = t; i < n; i += 256) {
    atomicAdd(&cd[cl[i] >> 8], 1);
    atomicAdd(&cs[rw[i] >> 8], 1);
  }
  __syncthreads();
  int* bd = blockCnt + (size_t)(r * 2 + 0) * SCAN_L;
  int* bs = blockCnt + (size_t)(r * 2 + 1) * SCAN_L;
  for (int i = t; i < NBIN; i += 256) {
    bd[i * NBLK + blk] = cd[i];
    bs[i * NBLK + blk] = cs[i];
  }
}

__global__ __launch_bounds__(256) void scan_pass1(const int* __restrict__ blockCnt,
                                                  int* __restrict__ chunkSum) {
  const int r2 = blockIdx.y, chunk = blockIdx.x, t = threadIdx.x;
  const int* a = blockCnt + (size_t)r2 * SCAN_L + chunk * SCHUNK;
  const int n = min(SCHUNK, SCAN_L - chunk * SCHUNK);
  int s = 0;
  for (int i = t; i < n; i += 256) s += a[i];
  __shared__ int sm[256];
  sm[t] = s;
  __syncthreads();
  #pragma unroll
  for (int off = 128; off > 0; off >>= 1) {
    if (t < off) sm[t] += sm[t + off];
    __syncthreads();
  }
  if (t == 0) chunkSum[r2 * NSCH + chunk] = sm[0];
}

__global__ __launch_bounds__(512) void scan_pass2(int* __restrict__ chunkSum,
                                                  int* __restrict__ bucketBase) {
  const int t = threadIdx.x;
  __shared__ int sm[8 * NSCH];
  if (t < 8 * NSCH) sm[t] = chunkSum[t];
  __syncthreads();
  if (t < 8) {
    int run = 0;
    for (int j = 0; j < NSCH; ++j) {
      int v = sm[t * NSCH + j];
      sm[t * NSCH + j] = run;
      run += v;
    }
    bucketBase[t * (NBIN + 1) + NBIN] = NE;
  }
  __syncthreads();
  if (t < 8 * NSCH) chunkSum[t] = sm[t];
}

__global__ __launch_bounds__(256) void scan_pass3(int* __restrict__ blockCnt,
                                                  const int* __restrict__ chunkSum,
                                                  int* __restrict__ bucketBase) {
  const int r2 = blockIdx.y, chunk = blockIdx.x, t = threadIdx.x;
  int* a = blockCnt + (size_t)r2 * SCAN_L + chunk * SCHUNK;
  const int gbase = chunk * SCHUNK;
  const int n = min(SCHUNK, SCAN_L - gbase);
  const int idx0 = t * 8;
  int v[8];
  int s = 0;
  #pragma unroll
  for (int j = 0; j < 8; ++j) {
    int id = idx0 + j;
    v[j] = (id < n) ? a[id] : 0;
    s += v[j];
  }
  __shared__ int sm[256];
  sm[t] = s;
  __syncthreads();
  for (int off = 1; off < 256; off <<= 1) {
    int x = (t >= off) ? sm[t - off] : 0;
    __syncthreads();
    sm[t] += x;
    __syncthreads();
  }
  int pre = ((t == 0) ? 0 : sm[t - 1]) + chunkSum[r2 * NSCH + chunk];
  #pragma unroll
  for (int j = 0; j < 8; ++j) {
    int id = idx0 + j;
    if (id < n) {
      int val = v[j];
      a[id] = pre;
      int g = gbase + id;
      if (g % NBLK == 0) bucketBase[r2 * (NBIN + 1) + g / NBLK] = pre;
      pre += val;
    }
  }
}

__global__ __launch_bounds__(256) void p1_scatter(Ptr4 rows, Ptr4 cols,
                                                  const int* __restrict__ blockCnt,
                                                  unsigned* __restrict__ pairD,
                                                  u8* __restrict__ srcb) {
  const int r = blockIdx.y, blk = blockIdx.x, t = threadIdx.x;
  const int e0 = blk * CH;
  const int n = min(CH, NE - e0);
  const int* rw = rows.p[r] + e0;
  const int* cl = cols.p[r] + e0;

  __shared__ int cnt[256], sc[256], lofs[256], cnt2[256], baseT[256];
  __shared__ unsigned pr[CH];
  __shared__ u8 binb[CH];
  __shared__ u8 pay8[CH];

  // ---------- dst side ----------
  cnt[t] = 0; cnt2[t] = 0;
  __syncthreads();
  for (int i = t; i < n; i += 256) atomicAdd(&cnt[cl[i] >> 8], 1);
  __syncthreads();
  sc[t] = cnt[t];
  __syncthreads();
  for (int off = 1; off < 256; off <<= 1) {
    int v = (t >= off) ? sc[t - off] : 0;
    __syncthreads();
    sc[t] += v;
    __syncthreads();
  }
  lofs[t] = (t == 0) ? 0 : sc[t - 1];
  if (t < NBIN) baseT[t] = blockCnt[(size_t)(r * 2 + 0) * SCAN_L + t * NBLK + blk];
  __syncthreads();
  for (int i = t; i < n; i += 256) {
    int c = cl[i];
    int bin = c >> 8;
    int rank = atomicAdd(&cnt2[bin], 1);
    int p = lofs[bin] + rank;
    pr[p] = ((unsigned)(c & 255) << 16) | (unsigned)rw[i];
    binb[p] = (u8)bin;
  }
  __syncthreads();
  {
    unsigned* pd = pairD + (size_t)r * NE;
    for (int i = t; i < n; i += 256) {
      int bin = binb[i];
      pd[baseT[bin] + (i - lofs[bin])] = pr[i];
    }
  }
  __syncthreads();

  // ---------- src side ----------
  cnt[t] = 0; cnt2[t] = 0;
  __syncthreads();
  for (int i = t; i < n; i += 256) atomicAdd(&cnt[rw[i] >> 8], 1);
  __syncthreads();
  sc[t] = cnt[t];
  __syncthreads();
  for (int off = 1; off < 256; off <<= 1) {
    int v = (t >= off) ? sc[t - off] : 0;
    __syncthreads();
    sc[t] += v;
    __syncthreads();
  }
  lofs[t] = (t == 0) ? 0 : sc[t - 1];
  if (t < NBIN) baseT[t] = blockCnt[(size_t)(r * 2 + 1) * SCAN_L + t * NBLK + blk];
  __syncthreads();
  for (int i = t; i < n; i += 256) {
    int sv = rw[i];
    int bin = sv >> 8;
    int rank = atomicAdd(&cnt2[bin], 1);
    int p = lofs[bin] + rank;
    pay8[p] = (u8)(sv & 255);
    binb[p] = (u8)bin;
  }
  __syncthreads();
  {
    u8* sb = srcb + (size_t)r * NE;
    for (int i = t; i < n; i += 256) {
      int bin = binb[i];
      sb[baseT[bin] + (i - lofs[bin])] = pay8[i];
    }
  }
}

__global__ __launch_bounds__(256) void p2_csr(const unsigned* __restrict__ pairD,
                                              const int* __restrict__ bucketBase,
                                              u16* __restrict__ srcidx,
                                              int* __restrict__ rowptr,
                                              float* __restrict__ dinvD) {
  const int r = blockIdx.y, bin = blockIdx.x, t = threadIdx.x;
  const int* bb = bucketBase + (r * 2 + 0) * (NBIN + 1);
  const int base = bb[bin], next = bb[bin + 1];
  const int span = next - base;
  const unsigned* pd = pairD + (size_t)r * NE + base;

  __shared__ int cnt[256], sc[256], ex[256], cnt2[256];
  __shared__ u16 lsrc[CAP2];
  cnt[t] = 0; cnt2[t] = 0;
  __syncthreads();
  for (int i = t; i < span; i += 256) atomicAdd(&cnt[pd[i] >> 16], 1);
  __syncthreads();
  sc[t] = cnt[t];
  __syncthreads();
  for (int off = 1; off < 256; off <<= 1) {
    int v = (t >= off) ? sc[t - off] : 0;
    __syncthreads();
    sc[t] += v;
    __syncthreads();
  }
  ex[t] = (t == 0) ? 0 : sc[t - 1];
  __syncthreads();

  const int node = (bin << 8) + t;
  if (node < NV) {
    rowptr[r * (NV + 1) + node] = base + ex[t];
    float deg = (float)cnt[t];
    dinvD[r * NV + node] = (r < 2) ? rsqrtf(deg + 1.f)
                                   : (deg > 0.f ? rsqrtf(deg) : 0.f);
  }
  if (bin == NBIN - 1 && t == 0) rowptr[r * (NV + 1) + NV] = NE;

  u16* so = srcidx + (size_t)r * NE + base;
  if (span <= CAP2) {
    for (int i = t; i < span; i += 256) {
      unsigned v = pd[i];
      int dl = v >> 16;
      int rank = atomicAdd(&cnt2[dl], 1);
      lsrc[ex[dl] + rank] = (u16)(v & 0xFFFFu);
    }
    __syncthreads();
    for (int i = t; i < span; i += 256) so[i] = lsrc[i];
  } else {
    for (int i = t; i < span; i += 256) {
      unsigned v = pd[i];
      int dl = v >> 16;
      int rank = atomicAdd(&cnt2[dl], 1);
      so[ex[dl] + rank] = (u16)(v & 0xFFFFu);
    }
  }
}

__global__ __launch_bounds__(256) void p2_srcdeg(const u8* __restrict__ srcb,
                                                 const int* __restrict__ bucketBase,
                                                 float* __restrict__ dinvS) {
  const int r = blockIdx.y, bin = blockIdx.x, t = threadIdx.x;
  const int* bb = bucketBase + (r * 2 + 1) * (NBIN + 1);
  const int base = bb[bin], next = bb[bin + 1];
  const int span = next - base;
  const u8* sb = srcb + (size_t)r * NE + base;
  __shared__ int cnt[256];
  cnt[t] = 0;
  __syncthreads();
  for (int i = t; i < span; i += 256) atomicAdd(&cnt[sb[i]], 1);
  __syncthreads();
  int node = (bin << 8) + t;
  if (node < NV) {
    float deg = (float)cnt[t];
    dinvS[r * NV + node] = (r < 2) ? rsqrtf(deg + 1.f)
                                   : (deg > 0.f ? rsqrtf(deg) : 0.f);
  }
}

// ================= dtype prep =================

__global__ __launch_bounds__(256) void xcvt(const float* __restrict__ x,
                                            bf16_t* __restrict__ xb, int n4) {
  int i = blockIdx.x * 256 + threadIdx.x;
  if (i < n4) {
    float4 v = *(const float4*)(x + (size_t)i * 4);
    unsigned a = (unsigned)f2bf(v.x) | ((unsigned)f2bf(v.y) << 16);
    unsigned b = (unsigned)f2bf(v.z) | ((unsigned)f2bf(v.w) << 16);
    *(uint2*)(xb + (size_t)i * 4) = make_uint2(a, b);
  }
}

// W[8][128k][128n] fp32 -> Wt[8][128n][128k] bf16 (transposed)
__global__ __launch_bounds__(256) void wprep(const float* __restrict__ Wsrc,
                                             bf16_t* __restrict__ Wt) {
  int idx = blockIdx.x * 256 + threadIdx.x;
  if (idx < 8 * 128 * 128) {
    int i = idx >> 14, n = (idx >> 7) & 127, k = idx & 127;
    Wt[idx] = f2bf(Wsrc[(size_t)i * 16384 + k * 128 + n]);
  }
}

// ================= MFMA dual GEMM: H_sliced = bf16( dS * (Xb @ W) ) =================
// Xb bf16 [M,128] row-major; Wt bf16 [128n][128k]. Output H in sliced layout
// H[slice][node][16] (slice = d>>4) for the XCD-partitioned pull.
__global__ __launch_bounds__(256) void gemm_mfma(
    const bf16_t* __restrict__ Xb0, const bf16_t* __restrict__ Wt0,
    const float* __restrict__ dS0, bf16_t* __restrict__ H0,
    const bf16_t* __restrict__ Xb1, const bf16_t* __restrict__ Wt1,
    const float* __restrict__ dS1, bf16_t* __restrict__ H1) {
  const bf16_t* Xb; const bf16_t* Wt; const float* dS; bf16_t* H;
  if (blockIdx.y == 0) { Xb = Xb0; Wt = Wt0; dS = dS0; H = H0; }
  else                 { Xb = Xb1; Wt = Wt1; dS = dS1; H = H1; }

  __shared__ bf16_t Xs[128][136];
  __shared__ bf16_t Wsh[128][136];
  __shared__ float sdS[128];
  const int t = threadIdx.x;
  const int row0 = blockIdx.x * 128;

  #pragma unroll
  for (int j = 0; j < 8; ++j) {
    int r = (t >> 4) + j * 16;
    int c = (t & 15) * 8;
    int gr = row0 + r;
    uint4 v = make_uint4(0u, 0u, 0u, 0u);
    if (gr < NV) v = *(const uint4*)(Xb + (size_t)gr * FD + c);
    *(uint4*)&Xs[r][c] = v;
    *(uint4*)&Wsh[r][c] = *(const uint4*)(Wt + (size_t)r * FD + c);
  }
  if (t < 128) {
    int g = row0 + t;
    sdS[t] = (g < NV) ? dS[g] : 0.f;
  }
  __syncthreads();

  const int wave = t >> 6, lane = t & 63;
  const int lr = lane & 15;
  const int lk = (lane >> 4) * 8;
  const int mb = wave * 32;

  f32x4 acc[2][8];
  #pragma unroll
  for (int m = 0; m < 2; ++m)
    #pragma unroll
    for (int n = 0; n < 8; ++n) acc[m][n] = (f32x4){0.f, 0.f, 0.f, 0.f};

  #pragma unroll
  for (int kc = 0; kc < 128; kc += 32) {
    bf16x8 a0 = *(const bf16x8*)&Xs[mb + lr][kc + lk];
    bf16x8 a1 = *(const bf16x8*)&Xs[mb + 16 + lr][kc + lk];
    bf16x8 b[8];
    #pragma unroll
    for (int n = 0; n < 8; ++n) b[n] = *(const bf16x8*)&Wsh[n * 16 + lr][kc + lk];
    #pragma unroll
    for (int n = 0; n < 8; ++n) {
      acc[0][n] = __builtin_amdgcn_mfma_f32_16x16x32_bf16(a0, b[n], acc[0][n], 0, 0, 0);
      acc[1][n] = __builtin_amdgcn_mfma_f32_16x16x32_bf16(a1, b[n], acc[1][n], 0, 0, 0);
    }
  }

  __syncthreads();   // done reading Wsh; reuse as bf16 output staging
  const int rgrp = (lane >> 4) * 4;
  #pragma unroll
  for (int m = 0; m < 2; ++m)
    #pragma unroll
    for (int n = 0; n < 8; ++n)
      #pragma unroll
      for (int j = 0; j < 4; ++j) {
        int rr = mb + m * 16 + rgrp + j;
        Wsh[rr][n * 16 + lr] = f2bf(acc[m][n][j] * sdS[rr]);
      }
  __syncthreads();

  #pragma unroll
  for (int j = 0; j < 8; ++j) {
    int r = (t >> 4) + j * 16;
    int c = (t & 15) * 8;
    int gr = row0 + r;
    if (gr < NV) {
      int slice = c >> 4;
      int off = c & 15;   // 0 or 8
      *(uint4*)(H + ((size_t)slice * NV + gr) * SDIM + off) = *(const uint4*)&Wsh[r][c];
    }
  }
}

// ================= XCD-sliced pull aggregation =================
// h in sliced layout [8][NV][16]; slice = blockIdx.x & 7 -> XCD affinity.
// Per wave: one node, one slice, both relations. Lane: es=lane>>3 (8 edges in
// flight), dp=lane&7 (2 dims each). Reduce via shfl_xor(8,16,32).
__global__ __launch_bounds__(256) void pull_sliced(
    const bf16_t* __restrict__ hA, const int* __restrict__ rpA, const u16* __restrict__ srcA,
    const float* __restrict__ dDA,
    const bf16_t* __restrict__ hB, const int* __restrict__ rpB, const u16* __restrict__ srcB,
    const float* __restrict__ dDB,
    const float* __restrict__ bA, const float* __restrict__ bB,
    bf16_t* __restrict__ Y) {
  const int slice = blockIdx.x & 7;
  const int grp   = blockIdx.x >> 3;
  const int wave  = threadIdx.x >> 6;
  const int lane  = threadIdx.x & 63;
  const int i = grp * 4 + wave;
  if (i >= NV) return;
  const int es = lane >> 3, dp = lane & 7;

  const bf16_t* hAs = hA + (size_t)slice * NV * SDIM;
  const bf16_t* hBs = hB + (size_t)slice * NV * SDIM;

  float ax = 0.f, ay = 0.f;
  if (es == 0) {  // self-loop term (relation A homogeneous; h pre-scaled by dS)
    unsigned v = *(const unsigned*)(hAs + ((size_t)i << 4) + dp * 2);
    ax = bflo(v); ay = bfhi(v);
  }
  {
    int p1 = rpA[i + 1];
    for (int p = rpA[i] + es; p < p1; p += 8) {
      int s = srcA[p];
      unsigned v = *(const unsigned*)(hAs + ((size_t)s << 4) + dp * 2);
      ax += bflo(v); ay += bfhi(v);
    }
  }
  float bx = 0.f, by = 0.f;
  {
    int p1 = rpB[i + 1];
    for (int p = rpB[i] + es; p < p1; p += 8) {
      int s = srcB[p];
      unsigned v = *(const unsigned*)(hBs + ((size_t)s << 4) + dp * 2);
      bx += bflo(v); by += bfhi(v);
    }
  }
  // reduce across es groups (same dp): masks 8, 16, 32
  #pragma unroll
  for (int m = 8; m <= 32; m <<= 1) {
    ax += __shfl_xor(ax, m, 64);
    ay += __shfl_xor(ay, m, 64);
    bx += __shfl_xor(bx, m, 64);
    by += __shfl_xor(by, m, 64);
  }
  if (es == 0) {
    float wA = dDA[i], wB = dDB[i];
    int d = slice * SDIM + dp * 2;
    float ox = fmaf(ax, wA, fmaf(bx, wB, bA[d] + bB[d]));
    float oy = fmaf(ay, wA, fmaf(by, wB, bA[d + 1] + bB[d + 1]));
    unsigned pk = (unsigned)f2bf(fmaxf(ox, 0.f)) | ((unsigned)f2bf(fmaxf(oy, 0.f)) << 16);
    *(unsigned*)(Y + (size_t)i * FD + d) = pk;
  }
}

// ================= final linear: Out[NV,64] = X[NV,128] @ lw^T + lb =================
__global__ __launch_bounds__(256) void linear64(const bf16_t* __restrict__ Xb,
                                                const float* __restrict__ lw,
                                                const float* __restrict__ lb,
                                                float* __restrict__ Out) {
  __shared__ float Wt[128][68];
  __shared__ float Xs[64][132];
  const int tid = threadIdx.x;
  const int row0 = blockIdx.x * 64;

  for (int i = tid * 4; i < 64 * 128; i += 1024) {
    float4 v = *(const float4*)(lw + i);
    int o = i >> 7, h = i & 127;
    Wt[h + 0][o] = v.x; Wt[h + 1][o] = v.y; Wt[h + 2][o] = v.z; Wt[h + 3][o] = v.w;
  }
  for (int i = tid * 8; i < 64 * 128; i += 2048) {
    int rr = i >> 7, cc = i & 127;
    int gr = row0 + rr;
    uint4 v = make_uint4(0u, 0u, 0u, 0u);
    if (gr < NV) v = *(const uint4*)(Xb + (size_t)gr * FD + cc);
    unsigned* pv = (unsigned*)&v;
    #pragma unroll
    for (int q = 0; q < 4; ++q) {
      Xs[rr][cc + q * 2]     = bflo(pv[q]);
      Xs[rr][cc + q * 2 + 1] = bfhi(pv[q]);
    }
  }
  __syncthreads();

  const int tx = tid & 15, ty = tid >> 4;
  float acc[4][4];
  #pragma unroll
  for (int i = 0; i < 4; ++i)
    #pragma unroll
    for (int j = 0; j < 4; ++j) acc[i][j] = 0.f;

  for (int k = 0; k < 128; k += 4) {
    float4 xr[4], w[4];
    #pragma unroll
    for (int i = 0; i < 4; ++i) xr[i] = *(const float4*)&Xs[ty * 4 + i][k];
    #pragma unroll
    for (int j = 0; j < 4; ++j) w[j] = *(const float4*)&Wt[k + j][tx * 4];
    #pragma unroll
    for (int i = 0; i < 4; ++i) {
      const float* xv = (const float*)&xr[i];
      #pragma unroll
      for (int j = 0; j < 4; ++j) {
        float x = xv[j];
        acc[i][0] = fmaf(x, w[j].x, acc[i][0]);
        acc[i][1] = fmaf(x, w[j].y, acc[i][1]);
        acc[i][2] = fmaf(x, w[j].z, acc[i][2]);
        acc[i][3] = fmaf(x, w[j].w, acc[i][3]);
      }
    }
  }
  float4 bias = *(const float4*)(lb + tx * 4);
  #pragma unroll
  for (int i = 0; i < 4; ++i) {
    int gr = row0 + ty * 4 + i;
    if (gr < NV) {
      *(float4*)(Out + (size_t)gr * NOUT + tx * 4) =
          make_float4(acc[i][0] + bias.x, acc[i][1] + bias.y,
                      acc[i][2] + bias.z, acc[i][3] + bias.w);
    }
  }
}

// ================= host orchestration =================

extern "C" void kernel_launch(void* const* d_in, const int* in_sizes, int n_in,
                              void* d_out, int out_size, void* d_ws, size_t ws_size,
                              hipStream_t stream) {
  const float* x_drug = (const float*)d_in[0];
  const float* x_dis  = (const float*)d_in[1];
  const int* ei[4] = { (const int*)d_in[2], (const int*)d_in[3],
                       (const int*)d_in[4], (const int*)d_in[5] };  // dd, ss, ds, sd
  const float* Ws = (const float*)d_in[6];
  const float* bs = (const float*)d_in[7];
  const float* lw = (const float*)d_in[8];
  const float* lb = (const float*)d_in[9];
  float* out = (float*)d_out;

  char* p = (char*)d_ws;
  auto take = [&](size_t bytes) -> void* {
    char* q = p;
    p += (bytes + 255) & ~(size_t)255;
    return (void*)q;
  };
  int* blockCnt   = (int*)take((size_t)8 * SCAN_L * sizeof(int));
  int* chunkSum   = (int*)take((size_t)8 * NSCH * sizeof(int));
  int* bucketBase = (int*)take((size_t)8 * (NBIN + 1) * sizeof(int));
  unsigned* pairD = (unsigned*)take((size_t)4 * NE * sizeof(unsigned));
  u8* srcb        = (u8*)take((size_t)4 * NE);
  u16* srcidx     = (u16*)take((size_t)4 * NE * sizeof(u16));
  int* rowptr     = (int*)take((size_t)4 * (NV + 1) * sizeof(int));
  float* dinvS    = (float*)take((size_t)4 * NV * sizeof(float));
  float* dinvD    = (float*)take((size_t)4 * NV * sizeof(float));
  bf16_t* hA  = (bf16_t*)take((size_t)NV * FD * sizeof(bf16_t));
  bf16_t* hB  = (bf16_t*)take((size_t)NV * FD * sizeof(bf16_t));
  bf16_t* xdb = (bf16_t*)take((size_t)NV * FD * sizeof(bf16_t));
  bf16_t* xsb = (bf16_t*)take((size_t)NV * FD * sizeof(bf16_t));
  bf16_t* Wtb = (bf16_t*)take((size_t)8 * FD * FD * sizeof(bf16_t));
  bf16_t* XD1 = (bf16_t*)take((size_t)NV * FD * sizeof(bf16_t));
  bf16_t* XS1 = (bf16_t*)take((size_t)NV * FD * sizeof(bf16_t));
  bf16_t* XD2 = (bf16_t*)take((size_t)NV * FD * sizeof(bf16_t));
  bf16_t* XS2 = (bf16_t*)take((size_t)NV * FD * sizeof(bf16_t));

  Ptr4 rows = {{ ei[0], ei[1], ei[2], ei[3] }};
  Ptr4 cols = {{ ei[0] + NE, ei[1] + NE, ei[2] + NE, ei[3] + NE }};

  // ---- prep ----
  p0_hist<<<dim3(NBLK, 4), 256, 0, stream>>>(rows, cols, blockCnt);
  scan_pass1<<<dim3(NSCH, 8), 256, 0, stream>>>(blockCnt, chunkSum);
  scan_pass2<<<1, 512, 0, stream>>>(chunkSum, bucketBase);
  scan_pass3<<<dim3(NSCH, 8), 256, 0, stream>>>(blockCnt, chunkSum, bucketBase);
  p1_scatter<<<dim3(NBLK, 4), 256, 0, stream>>>(rows, cols, blockCnt, pairD, srcb);
  p2_csr<<<dim3(NBIN, 4), 256, 0, stream>>>(pairD, bucketBase, srcidx, rowptr, dinvD);
  p2_srcdeg<<<dim3(NBIN, 4), 256, 0, stream>>>(srcb, bucketBase, dinvS);
  xcvt<<<(NV * FD / 4 + 255) / 256, 256, 0, stream>>>(x_drug, xdb, NV * FD / 4);
  xcvt<<<(NV * FD / 4 + 255) / 256, 256, 0, stream>>>(x_dis, xsb, NV * FD / 4);
  wprep<<<(8 * FD * FD + 255) / 256, 256, 0, stream>>>(Ws, Wtb);

  // ---- layers ----
  const dim3 GEMM_GRID((NV + 127) / 128, 2);
  const int PULL_GRID = ((NV + 3) / 4) * NSLICE;   // 12500 * 8 = 100000
  const int LIN_GRID = (NV + 63) / 64;
  const bf16_t* xd = xdb;
  const bf16_t* xs = xsb;
  bf16_t* nextd[2] = {XD1, XD2};
  bf16_t* nexts[2] = {XS1, XS2};
  for (int l = 0; l < 2; ++l) {
    const bf16_t* W0 = Wtb + (size_t)(l * 4 + 0) * FD * FD;
    const bf16_t* W1 = Wtb + (size_t)(l * 4 + 1) * FD * FD;
    const bf16_t* W2 = Wtb + (size_t)(l * 4 + 2) * FD * FD;
    const bf16_t* W3 = Wtb + (size_t)(l * 4 + 3) * FD * FD;
    const float* b0 = bs + (l * 4 + 0) * FD;
    const float* b1 = bs + (l * 4 + 1) * FD;
    const float* b2 = bs + (l * 4 + 2) * FD;
    const float* b3 = bs + (l * 4 + 3) * FD;

    gemm_mfma<<<GEMM_GRID, 256, 0, stream>>>(xd, W0, dinvS + 0 * NV, hA,
                                             xs, W3, dinvS + 3 * NV, hB);
    pull_sliced<<<PULL_GRID, 256, 0, stream>>>(
        hA, rowptr + 0 * (NV + 1), srcidx + (size_t)0 * NE, dinvD + 0 * NV,
        hB, rowptr + 3 * (NV + 1), srcidx + (size_t)3 * NE, dinvD + 3 * NV,
        b0, b3, nextd[l]);

    gemm_mfma<<<GEMM_GRID, 256, 0, stream>>>(xs, W1, dinvS + 1 * NV, hA,
                                             xd, W2, dinvS + 2 * NV, hB);
    pull_sliced<<<PULL_GRID, 256, 0, stream>>>(
        hA, rowptr + 1 * (NV + 1), srcidx + (size_t)1 * NE, dinvD + 1 * NV,
        hB, rowptr + 2 * (NV + 1), srcidx + (size_t)2 * NE, dinvD + 2 * NV,
        b1, b2, nexts[l]);

    xd = nextd[l];
    xs = nexts[l];
  }

  linear64<<<LIN_GRID, 256, 0, stream>>>(xd, lw, lb, out);
  linear64<<<LIN_GRID, 256, 0, stream>>>(xs, lw, lb, out + (size_t)NV * NOUT);
}

// Round 7
// 422.469 us; speedup vs baseline: 2.2765x; 2.2765x over previous
//
#include <hip/hip_runtime.h>

#define NV   50000
#define FD   128
#define NE   800000
#define NOUT 64
#define NBIN 196          // ceil(NV/256) coarse buckets of 256 nodes
#define CH   2048         // edges per block in P0/P1
#define NBLK 391          // ceil(NE/CH)
#define SCAN_L (NBIN * NBLK)
#define SCHUNK 2048       // elements per block in hierarchical scan
#define NSCH ((SCAN_L + SCHUNK - 1) / SCHUNK)   // 38
#define CAP2 12288        // LDS staging cap in P2 (avg span ~4083)

typedef unsigned short bf16_t;
typedef unsigned char  u8;
typedef __attribute__((ext_vector_type(8))) short bf16x8;
typedef __attribute__((ext_vector_type(4))) float f32x4;

__device__ __forceinline__ bf16_t f2bf(float f) {
  unsigned u = __builtin_bit_cast(unsigned, f);
  return (bf16_t)((u + 0x7fffu + ((u >> 16) & 1u)) >> 16);
}
__device__ __forceinline__ float bflo(unsigned v) { return __builtin_bit_cast(float, v << 16); }
__device__ __forceinline__ float bfhi(unsigned v) { return __builtin_bit_cast(float, v & 0xffff0000u); }

struct Ptr4 { const int* p[4]; };

// ================= bucket-sort based CSR build (no global atomics) =================

__global__ __launch_bounds__(256) void p0_hist(Ptr4 rows, Ptr4 cols,
                                               int* __restrict__ blockCnt) {
  const int r = blockIdx.y, blk = blockIdx.x, t = threadIdx.x;
  __shared__ int cd[NBIN], cs[NBIN];
  for (int i = t; i < NBIN; i += 256) { cd[i] = 0; cs[i] = 0; }
  __syncthreads();
  const int e0 = blk * CH;
  const int n = min(CH, NE - e0);
  const int* rw = rows.p[r] + e0;
  const int* cl = cols.p[r] + e0;
  for (int i = t; i < n; i += 256) {
    atomicAdd(&cd[cl[i] >> 8], 1);
    atomicAdd(&cs[rw[i] >> 8], 1);
  }
  __syncthreads();
  int* bd = blockCnt + (size_t)(r * 2 + 0) * SCAN_L;
  int* bs = blockCnt + (size_t)(r * 2 + 1) * SCAN_L;
  for (int i = t; i < NBIN; i += 256) {
    bd[i * NBLK + blk] = cd[i];
    bs[i * NBLK + blk] = cs[i];
  }
}

__global__ __launch_bounds__(256) void scan_pass1(const int* __restrict__ blockCnt,
                                                  int* __restrict__ chunkSum) {
  const int r2 = blockIdx.y, chunk = blockIdx.x, t = threadIdx.x;
  const int* a = blockCnt + (size_t)r2 * SCAN_L + chunk * SCHUNK;
  const int n = min(SCHUNK, SCAN_L - chunk * SCHUNK);
  int s = 0;
  for (int i = t; i < n; i += 256) s += a[i];
  __shared__ int sm[256];
  sm[t] = s;
  __syncthreads();
  #pragma unroll
  for (int off = 128; off > 0; off >>= 1) {
    if (t < off) sm[t] += sm[t + off];
    __syncthreads();
  }
  if (t == 0) chunkSum[r2 * NSCH + chunk] = sm[0];
}

__global__ __launch_bounds__(512) void scan_pass2(int* __restrict__ chunkSum,
                                                  int* __restrict__ bucketBase) {
  const int t = threadIdx.x;
  __shared__ int sm[8 * NSCH];
  if (t < 8 * NSCH) sm[t] = chunkSum[t];
  __syncthreads();
  if (t < 8) {
    int run = 0;
    for (int j = 0; j < NSCH; ++j) {
      int v = sm[t * NSCH + j];
      sm[t * NSCH + j] = run;
      run += v;
    }
    bucketBase[t * (NBIN + 1) + NBIN] = NE;
  }
  __syncthreads();
  if (t < 8 * NSCH) chunkSum[t] = sm[t];
}

__global__ __launch_bounds__(256) void scan_pass3(int* __restrict__ blockCnt,
                                                  const int* __restrict__ chunkSum,
                                                  int* __restrict__ bucketBase) {
  const int r2 = blockIdx.y, chunk = blockIdx.x, t = threadIdx.x;
  int* a = blockCnt + (size_t)r2 * SCAN_L + chunk * SCHUNK;
  const int gbase = chunk * SCHUNK;
  const int n = min(SCHUNK, SCAN_L - gbase);
  const int idx0 = t * 8;
  int v[8];
  int s = 0;
  #pragma unroll
  for (int j = 0; j < 8; ++j) {
    int id = idx0 + j;
    v[j] = (id < n) ? a[id] : 0;
    s += v[j];
  }
  __shared__ int sm[256];
  sm[t] = s;
  __syncthreads();
  for (int off = 1; off < 256; off <<= 1) {
    int x = (t >= off) ? sm[t - off] : 0;
    __syncthreads();
    sm[t] += x;
    __syncthreads();
  }
  int pre = ((t == 0) ? 0 : sm[t - 1]) + chunkSum[r2 * NSCH + chunk];
  #pragma unroll
  for (int j = 0; j < 8; ++j) {
    int id = idx0 + j;
    if (id < n) {
      int val = v[j];
      a[id] = pre;
      int g = gbase + id;
      if (g % NBLK == 0) bucketBase[r2 * (NBIN + 1) + g / NBLK] = pre;
      pre += val;
    }
  }
}

__global__ __launch_bounds__(256) void p1_scatter(Ptr4 rows, Ptr4 cols,
                                                  const int* __restrict__ blockCnt,
                                                  unsigned* __restrict__ pairD,
                                                  u8* __restrict__ srcb) {
  const int r = blockIdx.y, blk = blockIdx.x, t = threadIdx.x;
  const int e0 = blk * CH;
  const int n = min(CH, NE - e0);
  const int* rw = rows.p[r] + e0;
  const int* cl = cols.p[r] + e0;

  __shared__ int cnt[256], sc[256], lofs[256], cnt2[256], baseT[256];
  __shared__ unsigned pr[CH];
  __shared__ u8 binb[CH];
  __shared__ u8 pay8[CH];

  // ---------- dst side ----------
  cnt[t] = 0; cnt2[t] = 0;
  __syncthreads();
  for (int i = t; i < n; i += 256) atomicAdd(&cnt[cl[i] >> 8], 1);
  __syncthreads();
  sc[t] = cnt[t];
  __syncthreads();
  for (int off = 1; off < 256; off <<= 1) {
    int v = (t >= off) ? sc[t - off] : 0;
    __syncthreads();
    sc[t] += v;
    __syncthreads();
  }
  lofs[t] = (t == 0) ? 0 : sc[t - 1];
  if (t < NBIN) baseT[t] = blockCnt[(size_t)(r * 2 + 0) * SCAN_L + t * NBLK + blk];
  __syncthreads();
  for (int i = t; i < n; i += 256) {
    int c = cl[i];
    int bin = c >> 8;
    int rank = atomicAdd(&cnt2[bin], 1);
    int p = lofs[bin] + rank;
    pr[p] = ((unsigned)(c & 255) << 16) | (unsigned)rw[i];
    binb[p] = (u8)bin;
  }
  __syncthreads();
  {
    unsigned* pd = pairD + (size_t)r * NE;
    for (int i = t; i < n; i += 256) {
      int bin = binb[i];
      pd[baseT[bin] + (i - lofs[bin])] = pr[i];
    }
  }
  __syncthreads();

  // ---------- src side ----------
  cnt[t] = 0; cnt2[t] = 0;
  __syncthreads();
  for (int i = t; i < n; i += 256) atomicAdd(&cnt[rw[i] >> 8], 1);
  __syncthreads();
  sc[t] = cnt[t];
  __syncthreads();
  for (int off = 1; off < 256; off <<= 1) {
    int v = (t >= off) ? sc[t - off] : 0;
    __syncthreads();
    sc[t] += v;
    __syncthreads();
  }
  lofs[t] = (t == 0) ? 0 : sc[t - 1];
  if (t < NBIN) baseT[t] = blockCnt[(size_t)(r * 2 + 1) * SCAN_L + t * NBLK + blk];
  __syncthreads();
  for (int i = t; i < n; i += 256) {
    int sv = rw[i];
    int bin = sv >> 8;
    int rank = atomicAdd(&cnt2[bin], 1);
    int p = lofs[bin] + rank;
    pay8[p] = (u8)(sv & 255);
    binb[p] = (u8)bin;
  }
  __syncthreads();
  {
    u8* sb = srcb + (size_t)r * NE;
    for (int i = t; i < n; i += 256) {
      int bin = binb[i];
      sb[baseT[bin] + (i - lofs[bin])] = pay8[i];
    }
  }
}

// P2: per dst-bucket -> rowptr, dinvD, and node-sorted srcidx (int32 for SMEM loads)
__global__ __launch_bounds__(256) void p2_csr(const unsigned* __restrict__ pairD,
                                              const int* __restrict__ bucketBase,
                                              int* __restrict__ srcidx,
                                              int* __restrict__ rowptr,
                                              float* __restrict__ dinvD) {
  const int r = blockIdx.y, bin = blockIdx.x, t = threadIdx.x;
  const int* bb = bucketBase + (r * 2 + 0) * (NBIN + 1);
  const int base = bb[bin], next = bb[bin + 1];
  const int span = next - base;
  const unsigned* pd = pairD + (size_t)r * NE + base;

  __shared__ int cnt[256], sc[256], ex[256], cnt2[256];
  __shared__ int lsrc[CAP2];
  cnt[t] = 0; cnt2[t] = 0;
  __syncthreads();
  for (int i = t; i < span; i += 256) atomicAdd(&cnt[pd[i] >> 16], 1);
  __syncthreads();
  sc[t] = cnt[t];
  __syncthreads();
  for (int off = 1; off < 256; off <<= 1) {
    int v = (t >= off) ? sc[t - off] : 0;
    __syncthreads();
    sc[t] += v;
    __syncthreads();
  }
  ex[t] = (t == 0) ? 0 : sc[t - 1];
  __syncthreads();

  const int node = (bin << 8) + t;
  if (node < NV) {
    rowptr[r * (NV + 1) + node] = base + ex[t];
    float deg = (float)cnt[t];
    dinvD[r * NV + node] = (r < 2) ? rsqrtf(deg + 1.f)
                                   : (deg > 0.f ? rsqrtf(deg) : 0.f);
  }
  if (bin == NBIN - 1 && t == 0) rowptr[r * (NV + 1) + NV] = NE;

  int* so = srcidx + (size_t)r * NE + base;
  if (span <= CAP2) {
    for (int i = t; i < span; i += 256) {
      unsigned v = pd[i];
      int dl = v >> 16;
      int rank = atomicAdd(&cnt2[dl], 1);
      lsrc[ex[dl] + rank] = (int)(v & 0xFFFFu);
    }
    __syncthreads();
    for (int i = t; i < span; i += 256) so[i] = lsrc[i];
  } else {
    for (int i = t; i < span; i += 256) {
      unsigned v = pd[i];
      int dl = v >> 16;
      int rank = atomicAdd(&cnt2[dl], 1);
      so[ex[dl] + rank] = (int)(v & 0xFFFFu);
    }
  }
}

__global__ __launch_bounds__(256) void p2_srcdeg(const u8* __restrict__ srcb,
                                                 const int* __restrict__ bucketBase,
                                                 float* __restrict__ dinvS) {
  const int r = blockIdx.y, bin = blockIdx.x, t = threadIdx.x;
  const int* bb = bucketBase + (r * 2 + 1) * (NBIN + 1);
  const int base = bb[bin], next = bb[bin + 1];
  const int span = next - base;
  const u8* sb = srcb + (size_t)r * NE + base;
  __shared__ int cnt[256];
  cnt[t] = 0;
  __syncthreads();
  for (int i = t; i < span; i += 256) atomicAdd(&cnt[sb[i]], 1);
  __syncthreads();
  int node = (bin << 8) + t;
  if (node < NV) {
    float deg = (float)cnt[t];
    dinvS[r * NV + node] = (r < 2) ? rsqrtf(deg + 1.f)
                                   : (deg > 0.f ? rsqrtf(deg) : 0.f);
  }
}

// ================= dtype prep =================

__global__ __launch_bounds__(256) void xcvt(const float* __restrict__ x,
                                            bf16_t* __restrict__ xb, int n4) {
  int i = blockIdx.x * 256 + threadIdx.x;
  if (i < n4) {
    float4 v = *(const float4*)(x + (size_t)i * 4);
    unsigned a = (unsigned)f2bf(v.x) | ((unsigned)f2bf(v.y) << 16);
    unsigned b = (unsigned)f2bf(v.z) | ((unsigned)f2bf(v.w) << 16);
    *(uint2*)(xb + (size_t)i * 4) = make_uint2(a, b);
  }
}

// W[8][128k][128n] fp32 -> Wt[8][128n][128k] bf16 (transposed)
__global__ __launch_bounds__(256) void wprep(const float* __restrict__ Wsrc,
                                             bf16_t* __restrict__ Wt) {
  int idx = blockIdx.x * 256 + threadIdx.x;
  if (idx < 8 * 128 * 128) {
    int i = idx >> 14, n = (idx >> 7) & 127, k = idx & 127;
    Wt[idx] = f2bf(Wsrc[(size_t)i * 16384 + k * 128 + n]);
  }
}

// ================= MFMA quad GEMM: H = bf16( dS * (Xb @ W) ), row-major H ======
struct G4 {
  const bf16_t* X[4];
  const bf16_t* W[4];
  const float*  dS[4];
  bf16_t*       H[4];
};

__global__ __launch_bounds__(256) void gemm_quad(G4 g) {
  const int q = blockIdx.y;
  const bf16_t* Xb = g.X[q]; const bf16_t* Wt = g.W[q];
  const float* dS = g.dS[q]; bf16_t* H = g.H[q];

  __shared__ bf16_t Xs[128][136];
  __shared__ bf16_t Wsh[128][136];
  __shared__ float sdS[128];
  const int t = threadIdx.x;
  const int row0 = blockIdx.x * 128;

  #pragma unroll
  for (int j = 0; j < 8; ++j) {
    int r = (t >> 4) + j * 16;
    int c = (t & 15) * 8;
    int gr = row0 + r;
    uint4 v = make_uint4(0u, 0u, 0u, 0u);
    if (gr < NV) v = *(const uint4*)(Xb + (size_t)gr * FD + c);
    *(uint4*)&Xs[r][c] = v;
    *(uint4*)&Wsh[r][c] = *(const uint4*)(Wt + (size_t)r * FD + c);
  }
  if (t < 128) {
    int gidx = row0 + t;
    sdS[t] = (gidx < NV) ? dS[gidx] : 0.f;
  }
  __syncthreads();

  const int wave = t >> 6, lane = t & 63;
  const int lr = lane & 15;
  const int lk = (lane >> 4) * 8;
  const int mb = wave * 32;

  f32x4 acc[2][8];
  #pragma unroll
  for (int m = 0; m < 2; ++m)
    #pragma unroll
    for (int n = 0; n < 8; ++n) acc[m][n] = (f32x4){0.f, 0.f, 0.f, 0.f};

  #pragma unroll
  for (int kc = 0; kc < 128; kc += 32) {
    bf16x8 a0 = *(const bf16x8*)&Xs[mb + lr][kc + lk];
    bf16x8 a1 = *(const bf16x8*)&Xs[mb + 16 + lr][kc + lk];
    bf16x8 b[8];
    #pragma unroll
    for (int n = 0; n < 8; ++n) b[n] = *(const bf16x8*)&Wsh[n * 16 + lr][kc + lk];
    #pragma unroll
    for (int n = 0; n < 8; ++n) {
      acc[0][n] = __builtin_amdgcn_mfma_f32_16x16x32_bf16(a0, b[n], acc[0][n], 0, 0, 0);
      acc[1][n] = __builtin_amdgcn_mfma_f32_16x16x32_bf16(a1, b[n], acc[1][n], 0, 0, 0);
    }
  }

  __syncthreads();   // done reading Wsh; reuse as bf16 output staging
  const int rgrp = (lane >> 4) * 4;
  #pragma unroll
  for (int m = 0; m < 2; ++m)
    #pragma unroll
    for (int n = 0; n < 8; ++n)
      #pragma unroll
      for (int j = 0; j < 4; ++j) {
        int rr = mb + m * 16 + rgrp + j;
        Wsh[rr][n * 16 + lr] = f2bf(acc[m][n][j] * sdS[rr]);
      }
  __syncthreads();

  #pragma unroll
  for (int j = 0; j < 8; ++j) {
    int r = (t >> 4) + j * 16;
    int c = (t & 15) * 8;
    int gr = row0 + r;
    if (gr < NV) *(uint4*)(H + (size_t)gr * FD + c) = *(const uint4*)&Wsh[r][c];
  }
}

// ================= fused dual pull aggregation =================
// One wave per node; lane owns 2 dims. i / rowptr / indices are wave-uniform
// (scalar pipe); row loads are 8-deep batched for MLP.
__device__ __forceinline__ void gather8(const bf16_t* __restrict__ h,
                                        const int* __restrict__ src,
                                        int p0, int p1, int d,
                                        float& ax, float& ay) {
  int p = p0;
  while (p + 8 <= p1) {
    int s0 = src[p + 0], s1 = src[p + 1], s2 = src[p + 2], s3 = src[p + 3];
    int s4 = src[p + 4], s5 = src[p + 5], s6 = src[p + 6], s7 = src[p + 7];
    unsigned v0 = *(const unsigned*)(h + (s0 << 7) + d);
    unsigned v1 = *(const unsigned*)(h + (s1 << 7) + d);
    unsigned v2 = *(const unsigned*)(h + (s2 << 7) + d);
    unsigned v3 = *(const unsigned*)(h + (s3 << 7) + d);
    unsigned v4 = *(const unsigned*)(h + (s4 << 7) + d);
    unsigned v5 = *(const unsigned*)(h + (s5 << 7) + d);
    unsigned v6 = *(const unsigned*)(h + (s6 << 7) + d);
    unsigned v7 = *(const unsigned*)(h + (s7 << 7) + d);
    ax += bflo(v0); ay += bfhi(v0);
    ax += bflo(v1); ay += bfhi(v1);
    ax += bflo(v2); ay += bfhi(v2);
    ax += bflo(v3); ay += bfhi(v3);
    ax += bflo(v4); ay += bfhi(v4);
    ax += bflo(v5); ay += bfhi(v5);
    ax += bflo(v6); ay += bfhi(v6);
    ax += bflo(v7); ay += bfhi(v7);
    p += 8;
  }
  while (p + 2 <= p1) {
    int s0 = src[p], s1 = src[p + 1];
    unsigned v0 = *(const unsigned*)(h + (s0 << 7) + d);
    unsigned v1 = *(const unsigned*)(h + (s1 << 7) + d);
    ax += bflo(v0); ay += bfhi(v0);
    ax += bflo(v1); ay += bfhi(v1);
    p += 2;
  }
  if (p < p1) {
    int s = src[p];
    unsigned v = *(const unsigned*)(h + (s << 7) + d);
    ax += bflo(v); ay += bfhi(v);
  }
}

struct PullSide {
  const bf16_t* hA; const int* rpA; const int* srcA; const float* dDA;
  const bf16_t* hB; const int* rpB; const int* srcB; const float* dDB;
  const float* bA; const float* bB; bf16_t* Y;
};

__global__ __launch_bounds__(256) void pull_dual(PullSide s0, PullSide s1) {
  const PullSide& a = blockIdx.y ? s1 : s0;
  const int i = __builtin_amdgcn_readfirstlane(blockIdx.x * 4 + (threadIdx.x >> 6));
  if (i >= NV) return;
  const int lane = threadIdx.x & 63;
  const int d = lane * 2;

  float ax, ay;
  {  // self-loop term (relation A homogeneous; h pre-scaled by dS)
    unsigned v = *(const unsigned*)(a.hA + (i << 7) + d);
    ax = bflo(v); ay = bfhi(v);
  }
  gather8(a.hA, a.srcA, a.rpA[i], a.rpA[i + 1], d, ax, ay);
  float bx = 0.f, by = 0.f;
  gather8(a.hB, a.srcB, a.rpB[i], a.rpB[i + 1], d, bx, by);

  float wA = a.dDA[i], wB = a.dDB[i];
  float ox = fmaf(ax, wA, fmaf(bx, wB, a.bA[d] + a.bB[d]));
  float oy = fmaf(ay, wA, fmaf(by, wB, a.bA[d + 1] + a.bB[d + 1]));
  unsigned pk = (unsigned)f2bf(fmaxf(ox, 0.f)) | ((unsigned)f2bf(fmaxf(oy, 0.f)) << 16);
  *(unsigned*)(a.Y + (size_t)i * FD + d) = pk;
}

// ================= final linear: Out[NV,64] = X[NV,128] @ lw^T + lb =================
__global__ __launch_bounds__(256) void linear64(const bf16_t* __restrict__ Xb,
                                                const float* __restrict__ lw,
                                                const float* __restrict__ lb,
                                                float* __restrict__ Out) {
  __shared__ float Wt[128][68];
  __shared__ float Xs[64][132];
  const int tid = threadIdx.x;
  const int row0 = blockIdx.x * 64;

  for (int i = tid * 4; i < 64 * 128; i += 1024) {
    float4 v = *(const float4*)(lw + i);
    int o = i >> 7, h = i & 127;
    Wt[h + 0][o] = v.x; Wt[h + 1][o] = v.y; Wt[h + 2][o] = v.z; Wt[h + 3][o] = v.w;
  }
  for (int i = tid * 8; i < 64 * 128; i += 2048) {
    int rr = i >> 7, cc = i & 127;
    int gr = row0 + rr;
    uint4 v = make_uint4(0u, 0u, 0u, 0u);
    if (gr < NV) v = *(const uint4*)(Xb + (size_t)gr * FD + cc);
    unsigned* pv = (unsigned*)&v;
    #pragma unroll
    for (int q = 0; q < 4; ++q) {
      Xs[rr][cc + q * 2]     = bflo(pv[q]);
      Xs[rr][cc + q * 2 + 1] = bfhi(pv[q]);
    }
  }
  __syncthreads();

  const int tx = tid & 15, ty = tid >> 4;
  float acc[4][4];
  #pragma unroll
  for (int i = 0; i < 4; ++i)
    #pragma unroll
    for (int j = 0; j < 4; ++j) acc[i][j] = 0.f;

  for (int k = 0; k < 128; k += 4) {
    float4 xr[4], w[4];
    #pragma unroll
    for (int i = 0; i < 4; ++i) xr[i] = *(const float4*)&Xs[ty * 4 + i][k];
    #pragma unroll
    for (int j = 0; j < 4; ++j) w[j] = *(const float4*)&Wt[k + j][tx * 4];
    #pragma unroll
    for (int i = 0; i < 4; ++i) {
      const float* xv = (const float*)&xr[i];
      #pragma unroll
      for (int j = 0; j < 4; ++j) {
        float x = xv[j];
        acc[i][0] = fmaf(x, w[j].x, acc[i][0]);
        acc[i][1] = fmaf(x, w[j].y, acc[i][1]);
        acc[i][2] = fmaf(x, w[j].z, acc[i][2]);
        acc[i][3] = fmaf(x, w[j].w, acc[i][3]);
      }
    }
  }
  float4 bias = *(const float4*)(lb + tx * 4);
  #pragma unroll
  for (int i = 0; i < 4; ++i) {
    int gr = row0 + ty * 4 + i;
    if (gr < NV) {
      *(float4*)(Out + (size_t)gr * NOUT + tx * 4) =
          make_float4(acc[i][0] + bias.x, acc[i][1] + bias.y,
                      acc[i][2] + bias.z, acc[i][3] + bias.w);
    }
  }
}

// ================= host orchestration =================

extern "C" void kernel_launch(void* const* d_in, const int* in_sizes, int n_in,
                              void* d_out, int out_size, void* d_ws, size_t ws_size,
                              hipStream_t stream) {
  const float* x_drug = (const float*)d_in[0];
  const float* x_dis  = (const float*)d_in[1];
  const int* ei[4] = { (const int*)d_in[2], (const int*)d_in[3],
                       (const int*)d_in[4], (const int*)d_in[5] };  // dd, ss, ds, sd
  const float* Ws = (const float*)d_in[6];
  const float* bs = (const float*)d_in[7];
  const float* lw = (const float*)d_in[8];
  const float* lb = (const float*)d_in[9];
  float* out = (float*)d_out;

  char* p = (char*)d_ws;
  auto take = [&](size_t bytes) -> void* {
    char* q = p;
    p += (bytes + 255) & ~(size_t)255;
    return (void*)q;
  };
  int* blockCnt   = (int*)take((size_t)8 * SCAN_L * sizeof(int));
  int* chunkSum   = (int*)take((size_t)8 * NSCH * sizeof(int));
  int* bucketBase = (int*)take((size_t)8 * (NBIN + 1) * sizeof(int));
  unsigned* pairD = (unsigned*)take((size_t)4 * NE * sizeof(unsigned));
  u8* srcb        = (u8*)take((size_t)4 * NE);
  int* srcidx     = (int*)take((size_t)4 * NE * sizeof(int));
  int* rowptr     = (int*)take((size_t)4 * (NV + 1) * sizeof(int));
  float* dinvS    = (float*)take((size_t)4 * NV * sizeof(float));
  float* dinvD    = (float*)take((size_t)4 * NV * sizeof(float));
  bf16_t* hA  = (bf16_t*)take((size_t)NV * FD * sizeof(bf16_t));
  bf16_t* hB  = (bf16_t*)take((size_t)NV * FD * sizeof(bf16_t));
  bf16_t* hC  = (bf16_t*)take((size_t)NV * FD * sizeof(bf16_t));
  bf16_t* hD  = (bf16_t*)take((size_t)NV * FD * sizeof(bf16_t));
  bf16_t* xdb = (bf16_t*)take((size_t)NV * FD * sizeof(bf16_t));
  bf16_t* xsb = (bf16_t*)take((size_t)NV * FD * sizeof(bf16_t));
  bf16_t* Wtb = (bf16_t*)take((size_t)8 * FD * FD * sizeof(bf16_t));
  bf16_t* XD1 = (bf16_t*)take((size_t)NV * FD * sizeof(bf16_t));
  bf16_t* XS1 = (bf16_t*)take((size_t)NV * FD * sizeof(bf16_t));
  bf16_t* XD2 = (bf16_t*)take((size_t)NV * FD * sizeof(bf16_t));
  bf16_t* XS2 = (bf16_t*)take((size_t)NV * FD * sizeof(bf16_t));

  Ptr4 rows = {{ ei[0], ei[1], ei[2], ei[3] }};
  Ptr4 cols = {{ ei[0] + NE, ei[1] + NE, ei[2] + NE, ei[3] + NE }};

  // ---- prep ----
  p0_hist<<<dim3(NBLK, 4), 256, 0, stream>>>(rows, cols, blockCnt);
  scan_pass1<<<dim3(NSCH, 8), 256, 0, stream>>>(blockCnt, chunkSum);
  scan_pass2<<<1, 512, 0, stream>>>(chunkSum, bucketBase);
  scan_pass3<<<dim3(NSCH, 8), 256, 0, stream>>>(blockCnt, chunkSum, bucketBase);
  p1_scatter<<<dim3(NBLK, 4), 256, 0, stream>>>(rows, cols, blockCnt, pairD, srcb);
  p2_csr<<<dim3(NBIN, 4), 256, 0, stream>>>(pairD, bucketBase, srcidx, rowptr, dinvD);
  p2_srcdeg<<<dim3(NBIN, 4), 256, 0, stream>>>(srcb, bucketBase, dinvS);
  xcvt<<<(NV * FD / 4 + 255) / 256, 256, 0, stream>>>(x_drug, xdb, NV * FD / 4);
  xcvt<<<(NV * FD / 4 + 255) / 256, 256, 0, stream>>>(x_dis, xsb, NV * FD / 4);
  wprep<<<(8 * FD * FD + 255) / 256, 256, 0, stream>>>(Ws, Wtb);

  // ---- layers ----
  const dim3 GEMM_GRID((NV + 127) / 128, 4);   // 391 x 4
  const dim3 PULL_GRID((NV + 3) / 4, 2);       // 12500 x 2
  const int LIN_GRID = (NV + 63) / 64;
  const bf16_t* xd = xdb;
  const bf16_t* xs = xsb;
  bf16_t* nextd[2] = {XD1, XD2};
  bf16_t* nexts[2] = {XS1, XS2};
  for (int l = 0; l < 2; ++l) {
    const bf16_t* W0 = Wtb + (size_t)(l * 4 + 0) * FD * FD;
    const bf16_t* W1 = Wtb + (size_t)(l * 4 + 1) * FD * FD;
    const bf16_t* W2 = Wtb + (size_t)(l * 4 + 2) * FD * FD;
    const bf16_t* W3 = Wtb + (size_t)(l * 4 + 3) * FD * FD;
    const float* b0 = bs + (l * 4 + 0) * FD;
    const float* b1 = bs + (l * 4 + 1) * FD;
    const float* b2 = bs + (l * 4 + 2) * FD;
    const float* b3 = bs + (l * 4 + 3) * FD;

    // r0: drug@W0->hA ; r3: dis@W3->hB ; r1: dis@W1->hC ; r2: drug@W2->hD
    G4 g;
    g.X[0] = xd;  g.W[0] = W0; g.dS[0] = dinvS + 0 * NV; g.H[0] = hA;
    g.X[1] = xs;  g.W[1] = W3; g.dS[1] = dinvS + 3 * NV; g.H[1] = hB;
    g.X[2] = xs;  g.W[2] = W1; g.dS[2] = dinvS + 1 * NV; g.H[2] = hC;
    g.X[3] = xd;  g.W[3] = W2; g.dS[3] = dinvS + 2 * NV; g.H[3] = hD;
    gemm_quad<<<GEMM_GRID, 256, 0, stream>>>(g);

    PullSide pd_;  // drug: A=dd(r0), B=sd(r3)
    pd_.hA = hA; pd_.rpA = rowptr + 0 * (NV + 1); pd_.srcA = srcidx + (size_t)0 * NE;
    pd_.dDA = dinvD + 0 * NV;
    pd_.hB = hB; pd_.rpB = rowptr + 3 * (NV + 1); pd_.srcB = srcidx + (size_t)3 * NE;
    pd_.dDB = dinvD + 3 * NV;
    pd_.bA = b0; pd_.bB = b3; pd_.Y = nextd[l];
    PullSide ps_;  // dis: A=ss(r1), B=ds(r2)
    ps_.hA = hC; ps_.rpA = rowptr + 1 * (NV + 1); ps_.srcA = srcidx + (size_t)1 * NE;
    ps_.dDA = dinvD + 1 * NV;
    ps_.hB = hD; ps_.rpB = rowptr + 2 * (NV + 1); ps_.srcB = srcidx + (size_t)2 * NE;
    ps_.dDB = dinvD + 2 * NV;
    ps_.bA = b1; ps_.bB = b2; ps_.Y = nexts[l];
    pull_dual<<<PULL_GRID, 256, 0, stream>>>(pd_, ps_);

    xd = nextd[l];
    xs = nexts[l];
  }

  linear64<<<LIN_GRID, 256, 0, stream>>>(xd, lw, lb, out);
  linear64<<<LIN_GRID, 256, 0, stream>>>(xs, lw, lb, out + (size_t)NV * NOUT);
}